// Round 5
// baseline (2406.066 us; speedup 1.0000x reference)
//
#include <hip/hip_runtime.h>
#include <hip/hip_fp16.h>

typedef _Float16 half2_t __attribute__((ext_vector_type(2)));
typedef _Float16 half4_t __attribute__((ext_vector_type(4)));
typedef _Float16 half8_t __attribute__((ext_vector_type(8)));
typedef float floatx4 __attribute__((ext_vector_type(4)));
typedef unsigned long long u64;

#define B_   32
#define S_   512
#define D_   768
#define H_   384
#define H3_  1152      // 3*H
#define M_   (B_*S_)   // 16384
#define N2_  (2*H3_)   // 2304
#define TWOH_ 768
#define NWG_DIR 6
#define JSPAN 64       // j-slice per WG
#define NCHUNK 6144    // 32 b x 192 j-pairs per dir-slot

// ---- coherent (MALL-scope) store: 8B single-copy atomic {tag, payload} ----
__device__ __forceinline__ void store8_cc(void* p, u64 v) {
  asm volatile("global_store_dwordx2 %0, %1, off sc0 sc1"
               :: "v"((u64)p), "v"(v) : "memory");
}
// ---- 12 coherent 8B loads batched, one waitcnt (one MALL round trip) ----
__device__ __forceinline__ void load12_cc(const u64* base, int tid, u64 v[12]) {
  u64 a0 = (u64)(base + tid);
  u64 a1 = a0 + 1 * 4096, a2 = a0 + 2 * 4096, a3 = a0 + 3 * 4096;
  u64 a4 = a0 + 4 * 4096, a5 = a0 + 5 * 4096, a6 = a0 + 6 * 4096;
  u64 a7 = a0 + 7 * 4096, a8 = a0 + 8 * 4096, a9 = a0 + 9 * 4096;
  u64 a10 = a0 + 10 * 4096, a11 = a0 + 11 * 4096;
  asm volatile(
      "global_load_dwordx2 %0, %12, off sc0 sc1\n\t"
      "global_load_dwordx2 %1, %13, off sc0 sc1\n\t"
      "global_load_dwordx2 %2, %14, off sc0 sc1\n\t"
      "global_load_dwordx2 %3, %15, off sc0 sc1\n\t"
      "global_load_dwordx2 %4, %16, off sc0 sc1\n\t"
      "global_load_dwordx2 %5, %17, off sc0 sc1\n\t"
      "global_load_dwordx2 %6, %18, off sc0 sc1\n\t"
      "global_load_dwordx2 %7, %19, off sc0 sc1\n\t"
      "global_load_dwordx2 %8, %20, off sc0 sc1\n\t"
      "global_load_dwordx2 %9, %21, off sc0 sc1\n\t"
      "global_load_dwordx2 %10, %22, off sc0 sc1\n\t"
      "global_load_dwordx2 %11, %23, off sc0 sc1\n\t"
      "s_waitcnt vmcnt(0)"
      : "=&v"(v[0]), "=&v"(v[1]), "=&v"(v[2]), "=&v"(v[3]),
        "=&v"(v[4]), "=&v"(v[5]), "=&v"(v[6]), "=&v"(v[7]),
        "=&v"(v[8]), "=&v"(v[9]), "=&v"(v[10]), "=&v"(v[11])
      : "v"(a0), "v"(a1), "v"(a2), "v"(a3), "v"(a4), "v"(a5),
        "v"(a6), "v"(a7), "v"(a8), "v"(a9), "v"(a10), "v"(a11)
      : "memory");
}

// ---------------- generic fp32 -> fp16 convert (vec4) ----------------
__global__ void cvt_f32_f16_kernel(const float* __restrict__ src,
                                   _Float16* __restrict__ dst, int n4) {
  int i = blockIdx.x * blockDim.x + threadIdx.x;
  if (i >= n4) return;
  float4 v = ((const float4*)src)[i];
  half4_t h = {(_Float16)v.x, (_Float16)v.y, (_Float16)v.z, (_Float16)v.w};
  ((half4_t*)dst)[i] = h;
}

// ---------------- input-projection GEMM (fp16 MFMA) ----------------
__global__ __launch_bounds__(256) void gemm_xw_kernel(
    const _Float16* __restrict__ A, const _Float16* __restrict__ Bm,
    const float* __restrict__ bias_f, const float* __restrict__ bias_b,
    _Float16* __restrict__ xw) {
  __shared__ _Float16 As[64][40];
  __shared__ _Float16 Bs[64][40];
  const int m0 = blockIdx.x * 64, n0 = blockIdx.y * 64;
  const int tid = threadIdx.x, lane = tid & 63, w = tid >> 6;
  const int wm = w >> 1, wn = w & 1;
  const int q = lane >> 4, c = lane & 15;
  floatx4 acc[2][2] = {};

  const int t = tid & 127;
  const int srow = t >> 1, skh = (t & 1) * 16;
  const _Float16* gsrc =
      (tid < 128 ? A + (size_t)(m0 + srow) * D_ : Bm + (size_t)(n0 + srow) * D_) + skh;
  _Float16* ldst = (tid < 128) ? &As[srow][skh] : &Bs[srow][skh];

  for (int k0 = 0; k0 < D_; k0 += 32) {
    half8_t v0 = *(const half8_t*)(gsrc + k0);
    half8_t v1 = *(const half8_t*)(gsrc + k0 + 8);
    __syncthreads();
    *(half8_t*)ldst = v0;
    *(half8_t*)(ldst + 8) = v1;
    __syncthreads();
    half8_t a0 = *(const half8_t*)&As[wm * 32 + c][q * 8];
    half8_t a1 = *(const half8_t*)&As[wm * 32 + 16 + c][q * 8];
    half8_t b0 = *(const half8_t*)&Bs[wn * 32 + c][q * 8];
    half8_t b1 = *(const half8_t*)&Bs[wn * 32 + 16 + c][q * 8];
    acc[0][0] = __builtin_amdgcn_mfma_f32_16x16x32_f16(a0, b0, acc[0][0], 0, 0, 0);
    acc[0][1] = __builtin_amdgcn_mfma_f32_16x16x32_f16(a0, b1, acc[0][1], 0, 0, 0);
    acc[1][0] = __builtin_amdgcn_mfma_f32_16x16x32_f16(a1, b0, acc[1][0], 0, 0, 0);
    acc[1][1] = __builtin_amdgcn_mfma_f32_16x16x32_f16(a1, b1, acc[1][1], 0, 0, 0);
  }
  for (int mi = 0; mi < 2; ++mi)
    for (int ni = 0; ni < 2; ++ni)
      for (int r = 0; r < 4; ++r) {
        int m = m0 + wm * 32 + mi * 16 + q * 4 + r;
        int n = n0 + wn * 32 + ni * 16 + c;
        int dir = n >= H3_;
        int nn = n - dir * H3_;
        float bv = dir ? bias_b[nn] : bias_f[nn];
        float vv = acc[mi][ni][r] + bv;
        int s = m & (S_ - 1), bb = m >> 9;
        xw[(((size_t)dir * S_ + s) * B_ + bb) * H3_ + nn] = (_Float16)vv;
      }
}

// ---------------- GRU recurrence v4: tagged seqlock exchange, k-split waves ----
// 12 WGs = 2 dirs x 6 j-slices of 64. 512 threads = 8 waves = 4 jtiles x 2 khalves.
// Weights: 72 VGPRs/lane (resident). h exchange: 8B {tag|2xfp16} chunks via
// sc0sc1 stores (atomic, self-validating) + batched retry gathers. No flags,
// no drains, no cross-WG barrier. ghS (2 k-half partials) aliases dead hS.
__global__ __launch_bounds__(512, 2) void gru_mfma_kernel(
    const _Float16* __restrict__ xw,    // [2][512][32][1152]
    const _Float16* __restrict__ Whh,   // [2][1152][384] fp16 row-major
    const float* __restrict__ bhh_f, const float* __restrict__ bhh_b,
    u64* __restrict__ hglob,            // [2 dir][2 slot][6144] tagged chunks
    _Float16* __restrict__ out16) {     // [32][512][768]
  const int wg = blockIdx.x;
  const int dir = wg / NWG_DIR, wgj = wg % NWG_DIR;
  const int j0w = wgj * JSPAN;
  const int tid = threadIdx.x, lane = tid & 63, w = tid >> 6;
  const int kh = w & 1, jt = w >> 1;   // k-half (0..1), j-tile (0..3)
  const int c = lane & 15, q = lane >> 4;

  // hS [32][392] fp16 (25088 B) aliases ghS [2][3][32][68] f32 (52224 B):
  // hS is dead once the MFMA reads complete; sync choreography below.
  __shared__ __align__(16) char smemS[2 * 3 * 32 * 68 * 4];
  _Float16* hS = (_Float16*)smemS;
  typedef float ghArr[3][32][68];
  ghArr* ghS = (ghArr*)smemS;

  // ---- weight B-fragments: [gate][kt2] for this wave's (jt, kh) ----
  half8_t bfr[3][6];
  {
    const int jglob = j0w + jt * 16 + c;
#pragma unroll
    for (int g = 0; g < 3; ++g) {
      const _Float16* wp =
          Whh + ((size_t)dir * H3_ + g * H_ + jglob) * H_ + kh * 192 + q * 8;
#pragma unroll
      for (int kt2 = 0; kt2 < 6; ++kt2) bfr[g][kt2] = *(const half8_t*)(wp + kt2 * 32);
    }
  }
  const float* bhh = dir ? bhh_b : bhh_f;
  const int gb = tid >> 4, jq = tid & 15;  // gate-phase: b, j-quad
  const int jg4 = j0w + jq * 4;
  float br[4], bz[4], bn[4], hc[4];
#pragma unroll
  for (int i = 0; i < 4; ++i) {
    br[i] = bhh[jg4 + i];
    bz[i] = bhh[H_ + jg4 + i];
    bn[i] = bhh[2 * H_ + jg4 + i];
    hc[i] = 0.f;
  }
  // gather chunk -> (b, j-pair) map (loop-invariant)
  int gbch[12], gjp[12];
#pragma unroll
  for (int k = 0; k < 12; ++k) {
    int id = tid + k * 512;
    gbch[k] = id / 192;
    gjp[k] = id % 192;
  }

  // zero hS (h_0 = 0)
  for (int i = tid; i < 1568; i += 512) ((int4*)smemS)[i] = (int4){0, 0, 0, 0};

  for (int step = 0; step < S_; ++step) {
    const int t = dir ? (S_ - 1 - step) : step;

    // xw prefetch (plain cached loads, in flight across the gather)
    const _Float16* xp = xw + (((size_t)dir * S_ + t) * B_ + gb) * H3_ + jg4;
    half4_t xr4 = *(const half4_t*)xp;
    half4_t xz4 = *(const half4_t*)(xp + H_);
    half4_t xn4 = *(const half4_t*)(xp + 2 * H_);

    // retry-gather: loads are self-validating via in-chunk tags
    u64 v[12];
    if (step > 0) {
      const u64* slotp = hglob + ((size_t)dir * 2 + (step & 1)) * NCHUNK;
      for (;;) {
        load12_cc(slotp, tid, v);
        bool ok = true;
#pragma unroll
        for (int k = 0; k < 12; ++k) ok &= ((unsigned)v[k] == (unsigned)step);
        if (ok) break;
      }
    }
    __syncthreads();   // S1: prior gates' ghS reads complete (hS region writable)
    if (step > 0) {
#pragma unroll
      for (int k = 0; k < 12; ++k)
        *(int*)&hS[gbch[k] * 392 + gjp[k] * 2] = (int)(v[k] >> 32);
    }
    __syncthreads();   // S2: hS complete

    // MFMA: this wave's k-half partial over 3 gates x 2 btiles
    floatx4 acc[3][2] = {};
    {
      const _Float16* hrow = &hS[c * 392 + kh * 192 + q * 8];
#pragma unroll
      for (int kt2 = 0; kt2 < 6; ++kt2) {
        half8_t a0 = *(const half8_t*)(hrow + kt2 * 32);
        half8_t a1 = *(const half8_t*)(hrow + 16 * 392 + kt2 * 32);
#pragma unroll
        for (int g = 0; g < 3; ++g) {
          acc[g][0] = __builtin_amdgcn_mfma_f32_16x16x32_f16(a0, bfr[g][kt2], acc[g][0], 0, 0, 0);
          acc[g][1] = __builtin_amdgcn_mfma_f32_16x16x32_f16(a1, bfr[g][kt2], acc[g][1], 0, 0, 0);
        }
      }
    }
    __syncthreads();   // S3: all hS reads drained; ghS may overwrite hS region
#pragma unroll
    for (int g = 0; g < 3; ++g)
#pragma unroll
      for (int bt = 0; bt < 2; ++bt)
#pragma unroll
        for (int r = 0; r < 4; ++r)
          ghS[kh][g][bt * 16 + q * 4 + r][jt * 16 + c] = acc[g][bt][r];
    __syncthreads();   // S4: ghS complete

    // gate phase: thread (b=gb, j-quad=jq); sum the two k-half partials
    floatx4 arv = *(floatx4*)&ghS[0][0][gb][jq * 4];
    floatx4 azv = *(floatx4*)&ghS[0][1][gb][jq * 4];
    floatx4 anv = *(floatx4*)&ghS[0][2][gb][jq * 4];
    {
      floatx4 t0 = *(floatx4*)&ghS[1][0][gb][jq * 4];
      floatx4 t1 = *(floatx4*)&ghS[1][1][gb][jq * 4];
      floatx4 t2 = *(floatx4*)&ghS[1][2][gb][jq * 4];
      arv += t0; azv += t1; anv += t2;
    }
    half4_t hh;
#pragma unroll
    for (int i = 0; i < 4; ++i) {
      float rr = 1.f / (1.f + __expf(-((float)xr4[i] + arv[i] + br[i])));
      float zz = 1.f / (1.f + __expf(-((float)xz4[i] + azv[i] + bz[i])));
      float u = (float)xn4[i] + rr * (anv[i] + bn[i]);
      float e = __expf(-2.f * u);
      float nv = (1.f - e) / (1.f + e);
      hc[i] = (1.f - zz) * nv + zz * hc[i];
      hh[i] = (_Float16)hc[i];
    }
    // fire-and-forget tagged h chunks (tag = step+1, slot (step+1)&1)
    {
      u64* wslot = hglob + ((size_t)dir * 2 + ((step + 1) & 1)) * NCHUNK;
      int cb = gb * 192 + (jg4 >> 1);
      half2_t p0; p0.x = hh[0]; p0.y = hh[1];
      half2_t p1; p1.x = hh[2]; p1.y = hh[3];
      u64 c0 = ((u64)__builtin_bit_cast(unsigned, p0) << 32) | (unsigned)(step + 1);
      u64 c1 = ((u64)__builtin_bit_cast(unsigned, p1) << 32) | (unsigned)(step + 1);
      store8_cc(wslot + cb, c0);
      store8_cc(wslot + cb + 1, c1);
    }
    // out16 off the critical path
    *(half4_t*)&out16[((size_t)gb * S_ + t) * TWOH_ + dir * H_ + jg4] = hh;
  }
}

// ---------------- attention scores: tanh(out@Wattn^T + b) @ ctx ----------------
__global__ __launch_bounds__(256) void attn_score_kernel(
    const _Float16* __restrict__ A /*out16 [16384][768]*/,
    const _Float16* __restrict__ Bm /*Wattn16 [768][768]*/,
    const float* __restrict__ b_attn, const float* __restrict__ ctx,
    float* __restrict__ scores) {
  __shared__ _Float16 As[64][40];
  __shared__ _Float16 Bs[64][40];
  const int m0 = blockIdx.x * 64, n0 = blockIdx.y * 64;
  const int tid = threadIdx.x, lane = tid & 63, w = tid >> 6;
  const int wm = w >> 1, wn = w & 1;
  const int q = lane >> 4, c = lane & 15;
  floatx4 acc[2][2] = {};

  const int t = tid & 127;
  const int srow = t >> 1, skh = (t & 1) * 16;
  const _Float16* gsrc =
      (tid < 128 ? A + (size_t)(m0 + srow) * D_ : Bm + (size_t)(n0 + srow) * D_) + skh;
  _Float16* ldst = (tid < 128) ? &As[srow][skh] : &Bs[srow][skh];

  for (int k0 = 0; k0 < D_; k0 += 32) {
    half8_t v0 = *(const half8_t*)(gsrc + k0);
    half8_t v1 = *(const half8_t*)(gsrc + k0 + 8);
    __syncthreads();
    *(half8_t*)ldst = v0;
    *(half8_t*)(ldst + 8) = v1;
    __syncthreads();
    half8_t a0 = *(const half8_t*)&As[wm * 32 + c][q * 8];
    half8_t a1 = *(const half8_t*)&As[wm * 32 + 16 + c][q * 8];
    half8_t b0 = *(const half8_t*)&Bs[wn * 32 + c][q * 8];
    half8_t b1 = *(const half8_t*)&Bs[wn * 32 + 16 + c][q * 8];
    acc[0][0] = __builtin_amdgcn_mfma_f32_16x16x32_f16(a0, b0, acc[0][0], 0, 0, 0);
    acc[0][1] = __builtin_amdgcn_mfma_f32_16x16x32_f16(a0, b1, acc[0][1], 0, 0, 0);
    acc[1][0] = __builtin_amdgcn_mfma_f32_16x16x32_f16(a1, b0, acc[1][0], 0, 0, 0);
    acc[1][1] = __builtin_amdgcn_mfma_f32_16x16x32_f16(a1, b1, acc[1][1], 0, 0, 0);
  }
  for (int mi = 0; mi < 2; ++mi)
    for (int ni = 0; ni < 2; ++ni)
      for (int r = 0; r < 4; ++r) {
        int n = n0 + wn * 32 + ni * 16 + c;
        float vv = tanhf(acc[mi][ni][r] + b_attn[n]) * ctx[n];
        vv += __shfl_xor(vv, 1);
        vv += __shfl_xor(vv, 2);
        vv += __shfl_xor(vv, 4);
        vv += __shfl_xor(vv, 8);
        if (c == 0) {
          int m = m0 + wm * 32 + mi * 16 + q * 4 + r;
          atomicAdd(&scores[m], vv);
        }
      }
}

// ---------------- softmax over S per batch ----------------
__global__ __launch_bounds__(256) void softmax_kernel(const float* __restrict__ scores,
                                                      float* __restrict__ attn) {
  const int b = blockIdx.x, tid = threadIdx.x;
  __shared__ float red[8];
  float s0 = scores[b * S_ + tid], s1 = scores[b * S_ + 256 + tid];
  float m = fmaxf(s0, s1);
  for (int off = 1; off < 64; off <<= 1) m = fmaxf(m, __shfl_xor(m, off));
  int wv = tid >> 6;
  if ((tid & 63) == 0) red[wv] = m;
  __syncthreads();
  m = fmaxf(fmaxf(red[0], red[1]), fmaxf(red[2], red[3]));
  float e0 = expf(s0 - m), e1 = expf(s1 - m);
  float sum = e0 + e1;
  for (int off = 1; off < 64; off <<= 1) sum += __shfl_xor(sum, off);
  if ((tid & 63) == 0) red[4 + wv] = sum;
  __syncthreads();
  sum = red[4] + red[5] + red[6] + red[7];
  float inv = 1.0f / sum;
  attn[b * S_ + tid] = e0 * inv;
  attn[b * S_ + 256 + tid] = e1 * inv;
}

// ---------------- doc embedding: attn-weighted sum ----------------
__global__ __launch_bounds__(384) void doc_kernel(const float* __restrict__ attn,
                                                  const _Float16* __restrict__ out16,
                                                  float* __restrict__ dout) {
  const int b = blockIdx.x, tid = threadIdx.x;
  __shared__ float at[S_];
  for (int i = tid; i < S_; i += 384) at[i] = attn[b * S_ + i];
  __syncthreads();
  const half2_t* p = (const half2_t*)(out16 + (size_t)b * S_ * TWOH_) + tid;
  float acc0 = 0.f, acc1 = 0.f;
  for (int s = 0; s < S_; ++s) {
    half2_t h = p[(size_t)s * (TWOH_ / 2)];
    float wgt = at[s];
    acc0 += wgt * (float)h.x;
    acc1 += wgt * (float)h.y;
  }
  dout[b * TWOH_ + tid * 2] = acc0;
  dout[b * TWOH_ + tid * 2 + 1] = acc1;
}

// ---------------- host ----------------
extern "C" void kernel_launch(void* const* d_in, const int* in_sizes, int n_in,
                              void* d_out, int out_size, void* d_ws, size_t ws_size,
                              hipStream_t stream) {
  const float* ip     = (const float*)d_in[0];
  const float* W_ih_f = (const float*)d_in[1];
  const float* W_hh_f = (const float*)d_in[2];
  const float* b_ih_f = (const float*)d_in[3];
  const float* b_hh_f_p = (const float*)d_in[4];
  const float* W_ih_b = (const float*)d_in[5];
  const float* W_hh_b = (const float*)d_in[6];
  const float* b_ih_b = (const float*)d_in[7];
  const float* b_hh_b_p = (const float*)d_in[8];
  const float* W_attn = (const float*)d_in[9];
  const float* b_attn = (const float*)d_in[10];
  const float* context = (const float*)d_in[11];
  float* doc = (float*)d_out;

  char* ws = (char*)d_ws;
  size_t off = 0;
  auto alloc = [&](size_t bytes) {
    char* p = ws + off;
    off += (bytes + 255) & ~(size_t)255;
    return p;
  };
  _Float16* ip16    = (_Float16*)alloc((size_t)M_ * D_ * 2);          // 25.2 MB
  _Float16* Wih16   = (_Float16*)alloc((size_t)N2_ * D_ * 2);         // 3.5 MB
  _Float16* Whh16   = (_Float16*)alloc((size_t)2 * H3_ * H_ * 2);     // 1.8 MB
  _Float16* Wattn16 = (_Float16*)alloc((size_t)TWOH_ * TWOH_ * 2);    // 1.2 MB
  _Float16* xw      = (_Float16*)alloc((size_t)2 * S_ * B_ * H3_ * 2);// 75.5 MB
  _Float16* out16   = (_Float16*)alloc((size_t)B_ * S_ * TWOH_ * 2);  // 25.2 MB
  u64*      hglob   = (u64*)alloc((size_t)2 * 2 * NCHUNK * 8);        // 192 KB (tags: 0xAA poison never matches)
  float* scores     = (float*)alloc((size_t)M_ * 4);
  float* attn       = (float*)alloc((size_t)M_ * 4);

  // 1. converts
  cvt_f32_f16_kernel<<<(M_ * D_ / 4 + 255) / 256, 256, 0, stream>>>(ip, ip16, M_ * D_ / 4);
  cvt_f32_f16_kernel<<<(H3_ * D_ / 4 + 255) / 256, 256, 0, stream>>>(W_ih_f, Wih16, H3_ * D_ / 4);
  cvt_f32_f16_kernel<<<(H3_ * D_ / 4 + 255) / 256, 256, 0, stream>>>(W_ih_b, Wih16 + (size_t)H3_ * D_, H3_ * D_ / 4);
  cvt_f32_f16_kernel<<<(H3_ * H_ / 4 + 255) / 256, 256, 0, stream>>>(W_hh_f, Whh16, H3_ * H_ / 4);
  cvt_f32_f16_kernel<<<(H3_ * H_ / 4 + 255) / 256, 256, 0, stream>>>(W_hh_b, Whh16 + (size_t)H3_ * H_, H3_ * H_ / 4);
  cvt_f32_f16_kernel<<<(TWOH_ * TWOH_ / 4 + 255) / 256, 256, 0, stream>>>(W_attn, Wattn16, TWOH_ * TWOH_ / 4);

  // 2. input projection GEMM
  gemm_xw_kernel<<<dim3(M_ / 64, N2_ / 64), 256, 0, stream>>>(ip16, Wih16, b_ih_f, b_ih_b, xw);

  // 3. recurrence: cooperative launch (12 WGs); no memsets needed — chunks are
  //    tag-validated and 0xAA poison never equals a live tag (1..512)
  {
    const _Float16* xw_a = xw;
    const _Float16* whh_a = Whh16;
    const float* bf_a = b_hh_f_p;
    const float* bb_a = b_hh_b_p;
    u64* hg_a = hglob;
    _Float16* o16_a = out16;
    void* args[] = {(void*)&xw_a, (void*)&whh_a, (void*)&bf_a, (void*)&bb_a,
                    (void*)&hg_a, (void*)&o16_a};
    hipLaunchCooperativeKernel((const void*)gru_mfma_kernel, dim3(2 * NWG_DIR),
                               dim3(512), args, 0, stream);
  }

  // 4. attention scores
  hipMemsetAsync(scores, 0, (size_t)M_ * 4, stream);
  attn_score_kernel<<<dim3(M_ / 64, TWOH_ / 64), 256, 0, stream>>>(out16, Wattn16, b_attn, context, scores);

  // 5. softmax + weighted sum
  softmax_kernel<<<B_, 256, 0, stream>>>(scores, attn);
  doc_kernel<<<B_, 384, 0, stream>>>(attn, out16, doc);
}

// Round 7
// 2312.256 us; speedup vs baseline: 1.0406x; 1.0406x over previous
//
#include <hip/hip_runtime.h>
#include <hip/hip_fp16.h>

typedef _Float16 half2_t __attribute__((ext_vector_type(2)));
typedef _Float16 half4_t __attribute__((ext_vector_type(4)));
typedef _Float16 half8_t __attribute__((ext_vector_type(8)));
typedef float floatx4 __attribute__((ext_vector_type(4)));
typedef int intx4 __attribute__((ext_vector_type(4)));
typedef unsigned long long u64;

#define B_   32
#define S_   512
#define D_   768
#define H_   384
#define H3_  1152      // 3*H
#define M_   (B_*S_)   // 16384
#define N2_  (2*H3_)   // 2304
#define TWOH_ 768
#define NWG_DIR 6
#define JSPAN 64       // j-slice per WG
#define NCHUNK 6144    // 32 b x 192 j-pairs per dir-slot

// ---- coherent (MALL-scope) store: 8B single-copy atomic {payload|tag} ----
__device__ __forceinline__ void store8_cc(void* p, u64 v) {
  asm volatile("global_store_dwordx2 %0, %1, off sc0 sc1"
               :: "v"((u64)p), "v"(v) : "memory");
}
// ---- 12 coherent 8B loads batched, one waitcnt (one MALL round trip) ----
__device__ __forceinline__ void load12_cc(const u64* base, int tid, u64 v[12]) {
  u64 a0 = (u64)(base + tid);
  u64 a1 = a0 + 1 * 4096, a2 = a0 + 2 * 4096, a3 = a0 + 3 * 4096;
  u64 a4 = a0 + 4 * 4096, a5 = a0 + 5 * 4096, a6 = a0 + 6 * 4096;
  u64 a7 = a0 + 7 * 4096, a8 = a0 + 8 * 4096, a9 = a0 + 9 * 4096;
  u64 a10 = a0 + 10 * 4096, a11 = a0 + 11 * 4096;
  asm volatile(
      "global_load_dwordx2 %0, %12, off sc0 sc1\n\t"
      "global_load_dwordx2 %1, %13, off sc0 sc1\n\t"
      "global_load_dwordx2 %2, %14, off sc0 sc1\n\t"
      "global_load_dwordx2 %3, %15, off sc0 sc1\n\t"
      "global_load_dwordx2 %4, %16, off sc0 sc1\n\t"
      "global_load_dwordx2 %5, %17, off sc0 sc1\n\t"
      "global_load_dwordx2 %6, %18, off sc0 sc1\n\t"
      "global_load_dwordx2 %7, %19, off sc0 sc1\n\t"
      "global_load_dwordx2 %8, %20, off sc0 sc1\n\t"
      "global_load_dwordx2 %9, %21, off sc0 sc1\n\t"
      "global_load_dwordx2 %10, %22, off sc0 sc1\n\t"
      "global_load_dwordx2 %11, %23, off sc0 sc1\n\t"
      "s_waitcnt vmcnt(0)"
      : "=&v"(v[0]), "=&v"(v[1]), "=&v"(v[2]), "=&v"(v[3]),
        "=&v"(v[4]), "=&v"(v[5]), "=&v"(v[6]), "=&v"(v[7]),
        "=&v"(v[8]), "=&v"(v[9]), "=&v"(v[10]), "=&v"(v[11])
      : "v"(a0), "v"(a1), "v"(a2), "v"(a3), "v"(a4), "v"(a5),
        "v"(a6), "v"(a7), "v"(a8), "v"(a9), "v"(a10), "v"(a11)
      : "memory");
}

// ---------------- generic fp32 -> fp16 convert (vec4) ----------------
__global__ void cvt_f32_f16_kernel(const float* __restrict__ src,
                                   _Float16* __restrict__ dst, int n4) {
  int i = blockIdx.x * blockDim.x + threadIdx.x;
  if (i >= n4) return;
  float4 v = ((const float4*)src)[i];
  half4_t h = {(_Float16)v.x, (_Float16)v.y, (_Float16)v.z, (_Float16)v.w};
  ((half4_t*)dst)[i] = h;
}

// ---------------- input-projection GEMM: 128x128 tile, global_load_lds ----
__global__ __launch_bounds__(256) void gemm_xw_kernel(
    const _Float16* __restrict__ A, const _Float16* __restrict__ Bm,
    const float* __restrict__ bias_f, const float* __restrict__ bias_b,
    _Float16* __restrict__ xw) {
  __shared__ _Float16 As[128 * 32];
  __shared__ _Float16 Bs[128 * 32];
  const int m0 = blockIdx.x * 128, n0 = blockIdx.y * 128;
  const int tid = threadIdx.x, lane = tid & 63, w = tid >> 6;
  const int wm = w & 1, wn = w >> 1;   // 2x2 waves, 64x64 each
  const int c = lane & 15, q = lane >> 4;
  floatx4 acc[4][4] = {};

  const int r0 = tid >> 2, c0 = (tid & 3) * 8;  // 16B chunk per thread
  const _Float16* ga = A + (size_t)(m0 + r0) * D_ + c0;
  const _Float16* gb = Bm + (size_t)(n0 + r0) * D_ + c0;
  _Float16* la = As + tid * 8;
  _Float16* lb = Bs + tid * 8;

  for (int k0 = 0; k0 < D_; k0 += 32) {
    __syncthreads();
    __builtin_amdgcn_global_load_lds(
        (const __attribute__((address_space(1))) void*)(ga + k0),
        (__attribute__((address_space(3))) void*)la, 16, 0, 0);
    __builtin_amdgcn_global_load_lds(
        (const __attribute__((address_space(1))) void*)(ga + 64 * D_ + k0),
        (__attribute__((address_space(3))) void*)(la + 2048), 16, 0, 0);
    __builtin_amdgcn_global_load_lds(
        (const __attribute__((address_space(1))) void*)(gb + k0),
        (__attribute__((address_space(3))) void*)lb, 16, 0, 0);
    __builtin_amdgcn_global_load_lds(
        (const __attribute__((address_space(1))) void*)(gb + 64 * D_ + k0),
        (__attribute__((address_space(3))) void*)(lb + 2048), 16, 0, 0);
    __syncthreads();
    half8_t af[4], bfv[4];
#pragma unroll
    for (int i = 0; i < 4; ++i) {
      af[i] = *(const half8_t*)&As[(wm * 64 + i * 16 + c) * 32 + q * 8];
      bfv[i] = *(const half8_t*)&Bs[(wn * 64 + i * 16 + c) * 32 + q * 8];
    }
#pragma unroll
    for (int i = 0; i < 4; ++i)
#pragma unroll
      for (int j = 0; j < 4; ++j)
        acc[i][j] = __builtin_amdgcn_mfma_f32_16x16x32_f16(af[i], bfv[j], acc[i][j], 0, 0, 0);
  }
#pragma unroll
  for (int mi = 0; mi < 4; ++mi)
#pragma unroll
    for (int ni = 0; ni < 4; ++ni) {
      int n = n0 + wn * 64 + ni * 16 + c;
      int dir = n >= H3_;
      int nn = n - dir * H3_;
      float bv = dir ? bias_b[nn] : bias_f[nn];
#pragma unroll
      for (int r = 0; r < 4; ++r) {
        int m = m0 + wm * 64 + mi * 16 + q * 4 + r;
        int s = m & (S_ - 1), bb = m >> 9;
        xw[(((size_t)dir * S_ + s) * B_ + bb) * H3_ + nn] =
            (_Float16)(acc[mi][ni][r] + bv);
      }
    }
}

// ---- 36 named weight fragments (macro-expanded; arrays break asm pinning) ----
#define FOR_KT(X, g) X(g,0) X(g,1) X(g,2) X(g,3) X(g,4) X(g,5) \
                     X(g,6) X(g,7) X(g,8) X(g,9) X(g,10) X(g,11)
#define FOR_ALL(X) FOR_KT(X,0) FOR_KT(X,1) FOR_KT(X,2)

#define DECLF(g,kt) intx4 bfr_##g##_##kt;
#define LOADF(g,kt) { \
    const float* wp = Wsrc + (size_t)((g) * H_ + jglob) * H_ + (kt) * 32 + q * 8; \
    float4 f0 = *(const float4*)(wp); \
    float4 f1 = *(const float4*)(wp + 4); \
    half8_t hv = {(_Float16)f0.x, (_Float16)f0.y, (_Float16)f0.z, (_Float16)f0.w, \
                  (_Float16)f1.x, (_Float16)f1.y, (_Float16)f1.z, (_Float16)f1.w}; \
    bfr_##g##_##kt = __builtin_bit_cast(intx4, hv); }
#define PINF(g,kt) asm volatile("" : "+v"(bfr_##g##_##kt));
#define MFMA_KT(kt) { \
    half8_t a = *(const half8_t*)(hrow + (kt) * 32); \
    a0 = __builtin_amdgcn_mfma_f32_16x16x32_f16(a, __builtin_bit_cast(half8_t, bfr_0_##kt), a0, 0, 0, 0); \
    a1 = __builtin_amdgcn_mfma_f32_16x16x32_f16(a, __builtin_bit_cast(half8_t, bfr_1_##kt), a1, 0, 0, 0); \
    a2 = __builtin_amdgcn_mfma_f32_16x16x32_f16(a, __builtin_bit_cast(half8_t, bfr_2_##kt), a2, 0, 0, 0); }

// ---------------- GRU recurrence v5: tagged seqlock + pinned full-K weights ----
// 12 WGs = 2 dirs x 6 j-slices of 64. 512 threads = 8 waves = 2 btiles x 4 jtiles.
// Each wave: 3 gates x 12 K-frags = 144 weight VGPRs, pinned (named vars).
// h exchange: 8B {payload|tag} sc0sc1 chunks, fire-and-forget stores, batched
// retry gathers. Own j-slice short-circuits through LDS. 2 syncthreads/step.
__global__ __launch_bounds__(512) void gru_mfma_kernel(
    const _Float16* __restrict__ xw,     // [2][512][32][1152]
    const float* __restrict__ Whh_f, const float* __restrict__ Whh_b,
    const float* __restrict__ bhh_f, const float* __restrict__ bhh_b,
    u64* __restrict__ hglob,             // [2 dir][2 slot][6144] tagged chunks
    _Float16* __restrict__ out16) {      // [32][512][768]
  const int wg = blockIdx.x;
  const int dir = wg / NWG_DIR, wgj = wg % NWG_DIR;
  const int j0w = wgj * JSPAN;
  const int tid = threadIdx.x, lane = tid & 63, w = tid >> 6;
  const int bt = w & 1, jt = w >> 1;   // btile 0..1, jtile 0..3
  const int c = lane & 15, q = lane >> 4;

  __shared__ __align__(16) _Float16 hS[32 * 392];   // 25088 B
  __shared__ __align__(16) float ghS[3][32][68];    // 26112 B

  FOR_ALL(DECLF)
  {
    const float* Wsrc = dir ? Whh_b : Whh_f;
    const int jglob = j0w + jt * 16 + c;
    FOR_ALL(LOADF)
  }
  FOR_ALL(PINF)

  const float* bhh = dir ? bhh_b : bhh_f;
  const int gb = tid >> 4, jq = tid & 15;   // gate-phase: b, j-quad
  const int jg4 = j0w + jq * 4;
  float br[4], bz[4], bn[4], hc[4];
#pragma unroll
  for (int i = 0; i < 4; ++i) {
    br[i] = bhh[jg4 + i];
    bz[i] = bhh[H_ + jg4 + i];
    bn[i] = bhh[2 * H_ + jg4 + i];
    hc[i] = 0.f;
  }
  bool own[12];
  int gbch[12], gjp[12];
#pragma unroll
  for (int k = 0; k < 12; ++k) {
    int id = tid + k * 512;
    gbch[k] = id / 192;
    gjp[k] = id % 192;
    own[k] = (gjp[k] >> 5) == wgj;   // produced by this WG -> via LDS, skip MALL
  }

  for (int i = tid; i < 6272; i += 512) ((int*)hS)[i] = 0;  // h_0 = 0
  __syncthreads();

  for (int step = 0; step < S_; ++step) {
    const int t = dir ? (S_ - 1 - step) : step;

    // xw gate inputs (plain cached loads, in flight across the gather)
    const _Float16* xp = xw + (((size_t)dir * S_ + t) * B_ + gb) * H3_ + jg4;
    half4_t xr4 = *(const half4_t*)xp;
    half4_t xz4 = *(const half4_t*)(xp + H_);
    half4_t xn4 = *(const half4_t*)(xp + 2 * H_);

    // retry-gather remote chunks (self-validating tags; no ordering race)
    if (step > 0) {
      const u64* slotp = hglob + ((size_t)dir * 2 + (step & 1)) * NCHUNK;
      u64 v[12];
      for (;;) {
        load12_cc(slotp, tid, v);
        bool ok = true;
#pragma unroll
        for (int k = 0; k < 12; ++k)
          ok &= (own[k] || ((unsigned)v[k] == (unsigned)step));
        if (__all(ok)) break;
      }
#pragma unroll
      for (int k = 0; k < 12; ++k)
        if (!own[k]) *(int*)&hS[gbch[k] * 392 + gjp[k] * 2] = (int)(v[k] >> 32);
    }
    __syncthreads();   // S2: hS complete (also orders prev ghS reads vs writes)

    // MFMA: full-K, 3 gate-chains, A-frags from LDS, weights resident
    floatx4 a0 = {}, a1 = {}, a2 = {};
    {
      const _Float16* hrow = &hS[(bt * 16 + c) * 392 + q * 8];
      MFMA_KT(0) MFMA_KT(1) MFMA_KT(2) MFMA_KT(3)
      MFMA_KT(4) MFMA_KT(5) MFMA_KT(6) MFMA_KT(7)
      MFMA_KT(8) MFMA_KT(9) MFMA_KT(10) MFMA_KT(11)
    }
#pragma unroll
    for (int r = 0; r < 4; ++r) {
      int brow = bt * 16 + q * 4 + r;
      ghS[0][brow][jt * 16 + c] = a0[r];
      ghS[1][brow][jt * 16 + c] = a1[r];
      ghS[2][brow][jt * 16 + c] = a2[r];
    }
    __syncthreads();   // S4: ghS complete (also orders hS MFMA-reads vs gate hS-write)

    // gate phase: thread (b=gb, j-quad=jq)
    floatx4 arv = *(const floatx4*)&ghS[0][gb][jq * 4];
    floatx4 azv = *(const floatx4*)&ghS[1][gb][jq * 4];
    floatx4 anv = *(const floatx4*)&ghS[2][gb][jq * 4];
    half4_t hh;
#pragma unroll
    for (int i = 0; i < 4; ++i) {
      float rr = 1.f / (1.f + __expf(-((float)xr4[i] + arv[i] + br[i])));
      float zz = 1.f / (1.f + __expf(-((float)xz4[i] + azv[i] + bz[i])));
      float u = (float)xn4[i] + rr * (anv[i] + bn[i]);
      float e = __expf(-2.f * u);
      float nv = (1.f - e) / (1.f + e);   // tanh(u)
      hc[i] = (1.f - zz) * nv + zz * hc[i];
      hh[i] = (_Float16)hc[i];
    }
    // own slice straight into LDS for next step (never round-trips MALL)
    *(half4_t*)&hS[gb * 392 + jg4] = hh;
    // fire-and-forget tagged chunks for remote WGs (tag = step+1)
    {
      u64* wslot = hglob + ((size_t)dir * 2 + ((step + 1) & 1)) * NCHUNK;
      int cb = gb * 192 + (jg4 >> 1);
      half2_t p0; p0.x = hh[0]; p0.y = hh[1];
      half2_t p1; p1.x = hh[2]; p1.y = hh[3];
      u64 c0 = ((u64)__builtin_bit_cast(unsigned, p0) << 32) | (unsigned)(step + 1);
      u64 c1 = ((u64)__builtin_bit_cast(unsigned, p1) << 32) | (unsigned)(step + 1);
      store8_cc(wslot + cb, c0);
      store8_cc(wslot + cb + 1, c1);
    }
    // out16 off the critical path
    *(half4_t*)&out16[((size_t)gb * S_ + t) * TWOH_ + dir * H_ + jg4] = hh;
    // keep weight fragments loop-carried (no remat / reload from global)
    FOR_ALL(PINF)
  }
}

// ---------------- attention scores: tanh(out@Wattn^T + b) @ ctx ----------------
__global__ __launch_bounds__(256) void attn_score_kernel(
    const _Float16* __restrict__ A /*out16 [16384][768]*/,
    const _Float16* __restrict__ Bm /*Wattn16 [768][768]*/,
    const float* __restrict__ b_attn, const float* __restrict__ ctx,
    float* __restrict__ scores) {
  __shared__ _Float16 As[64][40];
  __shared__ _Float16 Bs[64][40];
  const int m0 = blockIdx.x * 64, n0 = blockIdx.y * 64;
  const int tid = threadIdx.x, lane = tid & 63, w = tid >> 6;
  const int wm = w >> 1, wn = w & 1;
  const int q = lane >> 4, c = lane & 15;
  floatx4 acc[2][2] = {};

  const int t = tid & 127;
  const int srow = t >> 1, skh = (t & 1) * 16;
  const _Float16* gsrc =
      (tid < 128 ? A + (size_t)(m0 + srow) * D_ : Bm + (size_t)(n0 + srow) * D_) + skh;
  _Float16* ldst = (tid < 128) ? &As[srow][skh] : &Bs[srow][skh];

  for (int k0 = 0; k0 < D_; k0 += 32) {
    half8_t v0 = *(const half8_t*)(gsrc + k0);
    half8_t v1 = *(const half8_t*)(gsrc + k0 + 8);
    __syncthreads();
    *(half8_t*)ldst = v0;
    *(half8_t*)(ldst + 8) = v1;
    __syncthreads();
    half8_t a0 = *(const half8_t*)&As[wm * 32 + c][q * 8];
    half8_t a1 = *(const half8_t*)&As[wm * 32 + 16 + c][q * 8];
    half8_t b0 = *(const half8_t*)&Bs[wn * 32 + c][q * 8];
    half8_t b1 = *(const half8_t*)&Bs[wn * 32 + 16 + c][q * 8];
    acc[0][0] = __builtin_amdgcn_mfma_f32_16x16x32_f16(a0, b0, acc[0][0], 0, 0, 0);
    acc[0][1] = __builtin_amdgcn_mfma_f32_16x16x32_f16(a0, b1, acc[0][1], 0, 0, 0);
    acc[1][0] = __builtin_amdgcn_mfma_f32_16x16x32_f16(a1, b0, acc[1][0], 0, 0, 0);
    acc[1][1] = __builtin_amdgcn_mfma_f32_16x16x32_f16(a1, b1, acc[1][1], 0, 0, 0);
  }
  for (int mi = 0; mi < 2; ++mi)
    for (int ni = 0; ni < 2; ++ni)
      for (int r = 0; r < 4; ++r) {
        int n = n0 + wn * 32 + ni * 16 + c;
        float vv = tanhf(acc[mi][ni][r] + b_attn[n]) * ctx[n];
        vv += __shfl_xor(vv, 1);
        vv += __shfl_xor(vv, 2);
        vv += __shfl_xor(vv, 4);
        vv += __shfl_xor(vv, 8);
        if (c == 0) {
          int m = m0 + wm * 32 + mi * 16 + q * 4 + r;
          atomicAdd(&scores[m], vv);
        }
      }
}

// ---------------- softmax over S per batch ----------------
__global__ __launch_bounds__(256) void softmax_kernel(const float* __restrict__ scores,
                                                      float* __restrict__ attn) {
  const int b = blockIdx.x, tid = threadIdx.x;
  __shared__ float red[8];
  float s0 = scores[b * S_ + tid], s1 = scores[b * S_ + 256 + tid];
  float m = fmaxf(s0, s1);
  for (int off = 1; off < 64; off <<= 1) m = fmaxf(m, __shfl_xor(m, off));
  int wv = tid >> 6;
  if ((tid & 63) == 0) red[wv] = m;
  __syncthreads();
  m = fmaxf(fmaxf(red[0], red[1]), fmaxf(red[2], red[3]));
  float e0 = expf(s0 - m), e1 = expf(s1 - m);
  float sum = e0 + e1;
  for (int off = 1; off < 64; off <<= 1) sum += __shfl_xor(sum, off);
  if ((tid & 63) == 0) red[4 + wv] = sum;
  __syncthreads();
  sum = red[4] + red[5] + red[6] + red[7];
  float inv = 1.0f / sum;
  attn[b * S_ + tid] = e0 * inv;
  attn[b * S_ + 256 + tid] = e1 * inv;
}

// ---------------- doc embedding: attn-weighted sum ----------------
__global__ __launch_bounds__(384) void doc_kernel(const float* __restrict__ attn,
                                                  const _Float16* __restrict__ out16,
                                                  float* __restrict__ dout) {
  const int b = blockIdx.x, tid = threadIdx.x;
  __shared__ float at[S_];
  for (int i = tid; i < S_; i += 384) at[i] = attn[b * S_ + i];
  __syncthreads();
  const half2_t* p = (const half2_t*)(out16 + (size_t)b * S_ * TWOH_) + tid;
  float acc0 = 0.f, acc1 = 0.f;
  for (int s = 0; s < S_; ++s) {
    half2_t h = p[(size_t)s * (TWOH_ / 2)];
    float wgt = at[s];
    acc0 += wgt * (float)h.x;
    acc1 += wgt * (float)h.y;
  }
  dout[b * TWOH_ + tid * 2] = acc0;
  dout[b * TWOH_ + tid * 2 + 1] = acc1;
}

// ---------------- host ----------------
extern "C" void kernel_launch(void* const* d_in, const int* in_sizes, int n_in,
                              void* d_out, int out_size, void* d_ws, size_t ws_size,
                              hipStream_t stream) {
  const float* ip     = (const float*)d_in[0];
  const float* W_ih_f = (const float*)d_in[1];
  const float* W_hh_f = (const float*)d_in[2];
  const float* b_ih_f = (const float*)d_in[3];
  const float* b_hh_f_p = (const float*)d_in[4];
  const float* W_ih_b = (const float*)d_in[5];
  const float* W_hh_b = (const float*)d_in[6];
  const float* b_ih_b = (const float*)d_in[7];
  const float* b_hh_b_p = (const float*)d_in[8];
  const float* W_attn = (const float*)d_in[9];
  const float* b_attn = (const float*)d_in[10];
  const float* context = (const float*)d_in[11];
  float* doc = (float*)d_out;

  char* ws = (char*)d_ws;
  size_t off = 0;
  auto alloc = [&](size_t bytes) {
    char* p = ws + off;
    off += (bytes + 255) & ~(size_t)255;
    return p;
  };
  _Float16* ip16    = (_Float16*)alloc((size_t)M_ * D_ * 2);          // 25.2 MB
  _Float16* Wih16   = (_Float16*)alloc((size_t)N2_ * D_ * 2);         // 3.5 MB
  _Float16* Wattn16 = (_Float16*)alloc((size_t)TWOH_ * TWOH_ * 2);    // 1.2 MB
  _Float16* xw      = (_Float16*)alloc((size_t)2 * S_ * B_ * H3_ * 2);// 75.5 MB
  _Float16* out16   = (_Float16*)alloc((size_t)B_ * S_ * TWOH_ * 2);  // 25.2 MB
  u64*      hglob   = (u64*)alloc((size_t)2 * 2 * NCHUNK * 8);        // 192 KB; 0xAA poison never matches a live tag
  float* scores     = (float*)alloc((size_t)M_ * 4);
  float* attn       = (float*)alloc((size_t)M_ * 4);

  // 1. converts (W_hh handled inline by the gru preload)
  cvt_f32_f16_kernel<<<(M_ * D_ / 4 + 255) / 256, 256, 0, stream>>>(ip, ip16, M_ * D_ / 4);
  cvt_f32_f16_kernel<<<(H3_ * D_ / 4 + 255) / 256, 256, 0, stream>>>(W_ih_f, Wih16, H3_ * D_ / 4);
  cvt_f32_f16_kernel<<<(H3_ * D_ / 4 + 255) / 256, 256, 0, stream>>>(W_ih_b, Wih16 + (size_t)H3_ * D_, H3_ * D_ / 4);
  cvt_f32_f16_kernel<<<(TWOH_ * TWOH_ / 4 + 255) / 256, 256, 0, stream>>>(W_attn, Wattn16, TWOH_ * TWOH_ / 4);

  // 2. input projection GEMM (128x128 tiles)
  gemm_xw_kernel<<<dim3(M_ / 128, N2_ / 128), 256, 0, stream>>>(ip16, Wih16, b_ih_f, b_ih_b, xw);

  // 3. recurrence: cooperative launch (12 WGs)
  {
    const _Float16* xw_a = xw;
    const float* whf_a = W_hh_f;
    const float* whb_a = W_hh_b;
    const float* bf_a = b_hh_f_p;
    const float* bb_a = b_hh_b_p;
    u64* hg_a = hglob;
    _Float16* o16_a = out16;
    void* args[] = {(void*)&xw_a, (void*)&whf_a, (void*)&whb_a, (void*)&bf_a,
                    (void*)&bb_a, (void*)&hg_a, (void*)&o16_a};
    hipLaunchCooperativeKernel((const void*)gru_mfma_kernel, dim3(2 * NWG_DIR),
                               dim3(512), args, 0, stream);
  }

  // 4. attention scores
  (void)hipMemsetAsync(scores, 0, (size_t)M_ * 4, stream);
  attn_score_kernel<<<dim3(M_ / 64, TWOH_ / 64), 256, 0, stream>>>(out16, Wattn16, b_attn, context, scores);

  // 5. softmax + weighted sum
  softmax_kernel<<<B_, 256, 0, stream>>>(scores, attn);
  doc_kernel<<<B_, 384, 0, stream>>>(attn, out16, doc);
}